// Round 8
// baseline (609.401 us; speedup 1.0000x reference)
//
#include <hip/hip_runtime.h>
#include <stdint.h>

// AngularTensorProduct: out[e,r,l3,c] = sum_k pf[k] * a1[e,r,l1[k],c] * a2[e,r,l2[k],c]
// MAX_L=3 -> A=20 monomials, K=84 combos. [E,R,A,C] f32, E=100000 R=8 C=16.
// Memory-bound: compulsory 3.07 GB; float4-copy ceiling 6.29 TB/s -> 488 us floor.
// Ladder: R1 609 | R3 float4+NT-store 601 (WRITE +12.5%, reverted) | R4 LDS both
// ways 578 | R5 direct cached scalar stores 541 = 5.67 TB/s (90% of copy) |
// R6 persistent reg-prefetch 620 REGRESSION (allocator serialized it) | R7 NT
// loads 552 null. R8 (final mechanism probe): global_load_lds direct staging
// (no reg round-trip / no ds_write) + double-buffered LDS + counted vmcnt(10)
// + raw s_barrier (no __syncthreads vmcnt(0) drain) -> next tile's 10 loads in
// flight under current tile's compute+store. Linear LDS dest required -> rule
// #21 both-sides swizzle: inverse-swizzled GLOBAL source (Q ^= (row&1)<<2,
// within-row 128B groups -> coalescing intact) + swizzled read (a ^ (r&1))
// restores 2-way (free) banks. Null here => 2R:1W controller mix is the
// roofline at ~90% of copy BW.

#define NA 20
#define NK 84
#define TR 8           // rows per tile
#define ROWF 320       // floats per row (A*C)
#define TILEF (TR*ROWF)   // 2560 floats per tensor-tile
#define TILEQ (TILEF/4)   // 640 float4
#define NTH 128
#define GPB 25         // tiles per block; 100000/25 = 4000 blocks

typedef float f32x4 __attribute__((ext_vector_type(4)));

namespace atp {

constexpr int lidx(int x, int y, int z) {
  int i = 0;
  for (int a = 0; a < x; ++a) i += (4 - a) * (5 - a) / 2;
  for (int b = 0; b < y; ++b) i += 4 - x - b;
  return i + z;
}

constexpr int combi(int n, int k) {
  int r = 1;
  for (int i = 1; i <= k; ++i) r = r * (n - k + i) / i;
  return r;
}

struct Tab {
  int l1[NK]; int l2[NK]; float pf[NK]; int cnt[NA]; int off[NA];
};

constexpr Tab make_tab() {
  Tab t{};
  int n = 0, m = 0;
  for (int x = 0; x <= 3; ++x)
    for (int y = 0; y <= 3 - x; ++y)
      for (int z = 0; z <= 3 - x - y; ++z) {
        t.off[m] = n;
        t.cnt[m] = (x + 1) * (y + 1) * (z + 1);
        for (int a = 0; a <= x; ++a)
          for (int b = 0; b <= y; ++b)
            for (int c = 0; c <= z; ++c) {
              t.l1[n] = lidx(a, b, c);
              t.l2[n] = lidx(x - a, y - b, z - c);
              t.pf[n] = (float)(combi(x, a) * combi(y, b) * combi(z, c));
              ++n;
            }
        ++m;
      }
  return t;
}

constexpr Tab T = make_tab();

}  // namespace atp

// Issue one tile's staging: 10 global_load_lds_dwordx4 per thread, LDS dest
// linear (wave-uniform base + lane*16 by construction: Q = k*128 + t).
// Global source carries the inverse swizzle (involution within each row).
__device__ __forceinline__ void stage_tile(const f32x4* __restrict__ g1,
                                           const f32x4* __restrict__ g2,
                                           float* ldsbuf, int t) {
#pragma unroll
  for (int k = 0; k < 5; ++k) {
    const int Q = k * NTH + t;           // 0..639, linear LDS float4 slot
    const int row = Q / 80;
    const int Qs = Q ^ ((row & 1) << 2); // same-row involution (128B groups)
    __builtin_amdgcn_global_load_lds(
        (const __attribute__((address_space(1))) uint32_t*)(g1 + Qs),
        (__attribute__((address_space(3))) uint32_t*)(ldsbuf + Q * 4), 16, 0, 0);
    __builtin_amdgcn_global_load_lds(
        (const __attribute__((address_space(1))) uint32_t*)(g2 + Qs),
        (__attribute__((address_space(3))) uint32_t*)(ldsbuf + TILEF + Q * 4), 16, 0, 0);
  }
}

__global__ __launch_bounds__(NTH) void atp_kernel(
    const float* __restrict__ in1, const float* __restrict__ in2,
    float* __restrict__ out) {
  __shared__ float lds[2][2][TILEF];  // [buf][tensor][data] = 40 KB -> 4 blk/CU

  const int t = threadIdx.x;
  const int r = t >> 4;
  const int c = t & 15;
  const int rx = r & 1;
  const long tile0 = (long)blockIdx.x * GPB;

  const f32x4* g1 = reinterpret_cast<const f32x4*>(in1) + tile0 * TILEQ;
  const f32x4* g2 = reinterpret_cast<const f32x4*>(in2) + tile0 * TILEQ;

  stage_tile(g1, g2, &lds[0][0][0], t);  // prologue: tile 0 in flight

  int buf = 0;
  for (int g = 0; g < GPB; ++g) {
    if (g + 1 < GPB) {
      // issue next tile into the other buffer; stays in flight across compute
      stage_tile(g1 + (g + 1) * TILEQ, g2 + (g + 1) * TILEQ,
                 &lds[buf ^ 1][0][0], t);
      // drain everything except the 10 newest (= next tile's loads):
      // current tile's loads + previous stores complete.
      asm volatile("s_waitcnt vmcnt(10)" ::: "memory");
    } else {
      asm volatile("s_waitcnt vmcnt(0)" ::: "memory");
    }
    __builtin_amdgcn_s_barrier();  // all waves confirmed current buf populated

    // gather with swizzled read index -> 2-way banks (free)
    const float* l1p = &lds[buf][0][r * ROWF];
    const float* l2p = &lds[buf][1][r * ROWF];
    float v1[NA], v2[NA];
#pragma unroll
    for (int a = 0; a < NA; ++a) v1[a] = l1p[((a ^ rx) << 4) + c];
#pragma unroll
    for (int a = 0; a < NA; ++a) v2[a] = l2p[((a ^ rx) << 4) + c];

    float* op = out + (tile0 + g) * TILEF + r * ROWF + c;
#pragma unroll
    for (int i3 = 0; i3 < NA; ++i3) {
      float acc = 0.f;
#pragma unroll
      for (int j = 0; j < atp::T.cnt[i3]; ++j) {
        const int k = atp::T.off[i3] + j;            // compile-time
        acc = fmaf(atp::T.pf[k] * v1[atp::T.l1[k]], v2[atp::T.l2[k]], acc);
      }
      op[i3 * 16] = acc;  // cached scalar store; L2 merges to full lines
    }
    __builtin_amdgcn_s_barrier();  // all reads of buf done before its reuse
    buf ^= 1;
  }
}

extern "C" void kernel_launch(void* const* d_in, const int* in_sizes, int n_in,
                              void* d_out, int out_size, void* d_ws, size_t ws_size,
                              hipStream_t stream) {
  const float* in1 = (const float*)d_in[0];
  const float* in2 = (const float*)d_in[1];
  float* out = (float*)d_out;
  const int n_tiles = out_size / TILEF;        // 100000
  const int blocks = n_tiles / GPB;            // 4000 (exact)
  atp_kernel<<<blocks, NTH, 0, stream>>>(in1, in2, out);
}

// Round 9
// 548.743 us; speedup vs baseline: 1.1105x; 1.1105x over previous
//
#include <hip/hip_runtime.h>

// AngularTensorProduct: out[e,r,l3,c] = sum_k pf[k] * a1[e,r,l1[k],c] * a2[e,r,l2[k],c]
// MAX_L=3 -> A=20 monomials, K=84 combos. [E,R,A,C] f32, E=100000 R=8 C=16.
// Memory-bound: compulsory 3.07 GB; float4-copy ceiling 6.29 TB/s -> 488 us floor.
//
// FINAL (= R5, the ladder's best at 541 us = 5.67 TB/s = 90% of copy ceiling):
//   R1 float2-gather 609 | R3 float4+NT-stores 601 (NT stores +12.5% WRITE:
//   partial-128B-line eviction defeats L2 merge -> never NT-store scattered
//   outputs) | R4 LDS-staged dense load+store 578 | R5 drop output restage,
//   direct cached scalar stores (L2 merges to exact-compulsory WRITE) 541 |
//   R6 persistent+reg-prefetch 620 (allocator serialized the pipeline, VGPR=52)
//   | R7 NT loads 552 null | R8 global_load_lds + dbuf + counted vmcnt +
//   both-sides swizzle 609 (bank conflicts 1.6e7->0 but 8 waves/CU of explicit
//   pipeline < 14 waves of block-churn TLP; vmcnt(10) also serializes store
//   retirement).
// Conclusion: traffic exact-compulsory both directions, no pipe >8% busy,
// occupancy uncorrelated (23-84% -> +-5%), three pipelining probes negative.
// 90% of copy BW on a 2R:1W mix is the platform ceiling for this op.

#define NA 20
#define NK 84
#define TR 8      // rows (e,r) per tile
#define ROWQ 80   // float4 per row (A*C = 320 f32)
#define PADQ 82   // padded row stride in float4 (328 f32; 328%32==8 -> 2-way banks, free per m136)
#define NTH 128   // threads per block = TR*16 channel tasks

typedef float f32x4 __attribute__((ext_vector_type(4)));

namespace atp {

// index of monomial (x,y,z) in the nested-loop l_list order
constexpr int lidx(int x, int y, int z) {
  int i = 0;
  for (int a = 0; a < x; ++a) i += (4 - a) * (5 - a) / 2;
  for (int b = 0; b < y; ++b) i += 4 - x - b;
  return i + z;
}

constexpr int combi(int n, int k) {
  int r = 1;
  for (int i = 1; i <= k; ++i) r = r * (n - k + i) / i;
  return r;
}

struct Tab {
  int l1[NK];
  int l2[NK];
  float pf[NK];
  int cnt[NA];
  int off[NA];
};

constexpr Tab make_tab() {
  Tab t{};
  int n = 0, m = 0;
  for (int x = 0; x <= 3; ++x)
    for (int y = 0; y <= 3 - x; ++y)
      for (int z = 0; z <= 3 - x - y; ++z) {
        t.off[m] = n;
        t.cnt[m] = (x + 1) * (y + 1) * (z + 1);
        for (int a = 0; a <= x; ++a)
          for (int b = 0; b <= y; ++b)
            for (int c = 0; c <= z; ++c) {
              t.l1[n] = lidx(a, b, c);
              t.l2[n] = lidx(x - a, y - b, z - c);
              t.pf[n] = (float)(combi(x, a) * combi(y, b) * combi(z, c));
              ++n;
            }
        ++m;
      }
  return t;
}

constexpr Tab T = make_tab();

}  // namespace atp

// Block = 128 threads = one 8-row tile (8*1280 B per tensor).
// Phase 1: stage both input tiles linearly into padded LDS (dense 1 KiB/wave
//          global segments — the 6.29 TB/s copy pattern).
// Phase 2: thread (row, c) gathers 20+20 scalars from LDS (2-way banks = free),
//          computes each of the 20 l3 outputs with compile-time register
//          indices (rule #20) and stores it DIRECTLY to global, interleaved
//          with the FMA chain. Scattered 4B cached stores merge to full lines
//          in L2 (verified: WRITE_SIZE exactly compulsory).
__global__ __launch_bounds__(NTH) void atp_kernel(
    const float* __restrict__ in1, const float* __restrict__ in2,
    float* __restrict__ out) {
  __shared__ f32x4 lds1[TR * PADQ];
  __shared__ f32x4 lds2[TR * PADQ];

  const int t = threadIdx.x;
  const long base_q = (long)blockIdx.x * (TR * ROWQ);  // float4 index
  const f32x4* g1 = reinterpret_cast<const f32x4*>(in1) + base_q;
  const f32x4* g2 = reinterpret_cast<const f32x4*>(in2) + base_q;

  // ---- phase 1: linear global -> padded LDS ----
#pragma unroll
  for (int k = 0; k < 5; ++k) {
    const int q = k * NTH + t;      // 0..639
    const int row = q / ROWQ;
    const int qq = q - row * ROWQ;
    lds1[row * PADQ + qq] = g1[q];
    lds2[row * PADQ + qq] = g2[q];
  }
  __syncthreads();

  // ---- phase 2: per-(row,c) compute from LDS, direct global stores ----
  const int row = t >> 4;
  const int c = t & 15;
  const float* l1p = reinterpret_cast<const float*>(lds1) + row * (PADQ * 4) + c;
  const float* l2p = reinterpret_cast<const float*>(lds2) + row * (PADQ * 4) + c;
  float* op = out + base_q * 4 + row * (ROWQ * 4) + c;

  float v1[NA], v2[NA];
#pragma unroll
  for (int a = 0; a < NA; ++a) v1[a] = l1p[a * 16];
#pragma unroll
  for (int a = 0; a < NA; ++a) v2[a] = l2p[a * 16];

#pragma unroll
  for (int i3 = 0; i3 < NA; ++i3) {
    float acc = 0.f;
#pragma unroll
    for (int j = 0; j < atp::T.cnt[i3]; ++j) {
      const int k = atp::T.off[i3] + j;               // compile-time
      acc = fmaf(atp::T.pf[k] * v1[atp::T.l1[k]], v2[atp::T.l2[k]], acc);
    }
    op[i3 * 16] = acc;   // cached scalar store; L2 merges to full lines
  }
}

extern "C" void kernel_launch(void* const* d_in, const int* in_sizes, int n_in,
                              void* d_out, int out_size, void* d_ws, size_t ws_size,
                              hipStream_t stream) {
  const float* in1 = (const float*)d_in[0];
  const float* in2 = (const float*)d_in[1];
  float* out = (float*)d_out;
  // out_size = E*R*A*C f32; tiles of TR rows of A*C floats each
  const int n_tiles = out_size / (TR * NA * 16);  // = 100000
  atp_kernel<<<n_tiles, NTH, 0, stream>>>(in1, in2, out);
}